// Round 3
// baseline (504.585 us; speedup 1.0000x reference)
//
#include <hip/hip_runtime.h>
#include <hip/hip_bf16.h>

// LSTM cell: B=4096, IN=1024, H=2048.
// gates = [prev_h | x] @ W^T with W rows GATE-INTERLEAVED (row j = gate j&3, h j>>2),
// so the LSTM elementwise math fuses into the GEMM epilogue wave-locally.
// Pipeline: 1 pack kernel (fp32->bf16, restride+interleave), 1 fused GEMM+LSTM kernel.

#define BATCH 4096
#define INW   1024
#define HID   2048
#define GK    3072   // HID + INW
#define GN    8192   // 4*HID

typedef __attribute__((ext_vector_type(8))) short short8;
typedef __attribute__((ext_vector_type(4))) float floatx4;

__device__ __forceinline__ unsigned short f2bf(float f) {
    union { float f; unsigned u; } v; v.f = f;
    unsigned r = v.u + 0x7FFFu + ((v.u >> 16) & 1u);
    return (unsigned short)(r >> 16);
}
__device__ __forceinline__ float sigf(float x) {
    return 1.0f / (1.0f + __expf(-x));
}
__device__ __forceinline__ float tanhfast(float x) {
    float t = __expf(fminf(fmaxf(2.0f * x, -30.0f), 30.0f));
    return (t - 1.0f) / (t + 1.0f);
}

// ---- single fused fp32->bf16 pack: prev_h | x -> hx (stride GK); Wi..Wc -> Wb gate-interleaved ----
// float4-group counts: ph 4096*512=2097152, x 4096*256=1048576, each W 2048*768=1572864.
// All boundaries are multiples of 256 -> block-uniform branches.
__global__ __launch_bounds__(256) void pack_all(const float4* __restrict__ ph,
                                                const float4* __restrict__ x,
                                                const float4* __restrict__ Wi,
                                                const float4* __restrict__ Wf,
                                                const float4* __restrict__ Wo,
                                                const float4* __restrict__ Wc,
                                                unsigned short* __restrict__ hx,
                                                unsigned short* __restrict__ Wb) {
    long i = (long)blockIdx.x * 256 + threadIdx.x;
    float4 v;
    unsigned short* dst;
    if (i < 2097152L) {                       // prev_h: [4096,2048] -> hx[:, 0:2048]
        int r  = (int)(i >> 9);
        int c4 = (int)(i & 511);
        v = ph[i];
        dst = hx + (size_t)r * GK + (size_t)c4 * 4;
    } else if (i < 3145728L) {                // x: [4096,1024] -> hx[:, 2048:3072]
        long j = i - 2097152L;
        int r  = (int)(j >> 8);
        int c4 = (int)(j & 255);
        v = x[j];
        dst = hx + (size_t)r * GK + HID + (size_t)c4 * 4;
    } else {                                  // W_g: [2048,3072] -> Wb row (r*4+g)
        long j = i - 3145728L;
        int g  = (int)(j / 1572864L);
        long jj = j - (long)g * 1572864L;
        int r  = (int)(jj / 768);
        int c4 = (int)(jj - (long)r * 768);
        const float4* Wg = (g == 0) ? Wi : (g == 1) ? Wf : (g == 2) ? Wo : Wc;
        v = Wg[jj];
        dst = Wb + ((size_t)r * 4 + g) * GK + (size_t)c4 * 4;
    }
    ushort4 o;
    o.x = f2bf(v.x); o.y = f2bf(v.y); o.z = f2bf(v.z); o.w = f2bf(v.w);
    *(ushort4*)dst = o;
}

__device__ __forceinline__ void gld16(const unsigned short* g, unsigned short* l) {
    __builtin_amdgcn_global_load_lds((const __attribute__((address_space(1))) unsigned int*)g,
                                     (__attribute__((address_space(3))) unsigned int*)l,
                                     16, 0, 0);
}

// ---- fused GEMM (bf16 MFMA, fp32 acc) + LSTM elementwise epilogue ----
// A = hx [4096, 3072]; Bt = Wb [8192, 3072] gate-interleaved.
// Block computes a 128(batch) x 128(col) gates tile = 128 batch x 32 h x 4 gates,
// then applies sigmoid/tanh math and writes fp32 next_h / next_c.
__global__ __launch_bounds__(256) void gemm_lstm(const unsigned short* __restrict__ A,
                                                 const unsigned short* __restrict__ Bt,
                                                 const float* __restrict__ pc,
                                                 float* __restrict__ out) {
    __shared__ __attribute__((aligned(16))) unsigned short smem[128 * 32 * 2];  // 16 KB
    unsigned short* lA = smem;                 // 128x32 bf16
    unsigned short* lB = smem + 128 * 32;      // 128x32 bf16
    const int tid  = threadIdx.x;
    const int wave = tid >> 6;
    const int lane = tid & 63;
    const long row0 = (long)blockIdx.x * 128;   // batch tile
    const long col0 = (long)blockIdx.y * 128;   // interleaved-col tile

    const int sr = tid >> 2;
    const int sk = (tid & 3) << 3;
    const unsigned short* gA0 = A  + (row0 + sr)      * GK + sk;
    const unsigned short* gA1 = A  + (row0 + 64 + sr) * GK + sk;
    const unsigned short* gB0 = Bt + (col0 + sr)      * GK + sk;
    const unsigned short* gB1 = Bt + (col0 + 64 + sr) * GK + sk;
    unsigned short* lA0 = &lA[wave * 512];
    unsigned short* lA1 = &lA[2048 + wave * 512];
    unsigned short* lB0 = &lB[wave * 512];
    unsigned short* lB1 = &lB[2048 + wave * 512];

    floatx4 acc[4][4];
    #pragma unroll
    for (int mi = 0; mi < 4; mi++)
        #pragma unroll
        for (int ni = 0; ni < 4; ni++)
            acc[mi][ni] = (floatx4)(0.0f);

    const int mBase = (wave >> 1) << 6;   // batch quadrant
    const int nBase = (wave & 1) << 6;    // col quadrant
    const int fr = lane & 15;
    const int kq = (lane >> 4) << 3;

    for (int k0 = 0; k0 < GK; k0 += 32) {
        __syncthreads();
        gld16(gA0 + k0, lA0);
        gld16(gA1 + k0, lA1);
        gld16(gB0 + k0, lB0);
        gld16(gB1 + k0, lB1);
        __syncthreads();

        short8 af[4], bfv[4];
        #pragma unroll
        for (int mi = 0; mi < 4; mi++)
            af[mi] = *(const short8*)&lA[(mBase + mi * 16 + fr) * 32 + kq];
        #pragma unroll
        for (int ni = 0; ni < 4; ni++)
            bfv[ni] = *(const short8*)&lB[(nBase + ni * 16 + fr) * 32 + kq];
        #pragma unroll
        for (int mi = 0; mi < 4; mi++)
            #pragma unroll
            for (int ni = 0; ni < 4; ni++)
                acc[mi][ni] = __builtin_amdgcn_mfma_f32_16x16x32_bf16(af[mi], bfv[ni], acc[mi][ni], 0, 0, 0);
    }

    // ---- fused LSTM epilogue (wave-local LDS transpose) ----
    __syncthreads();  // all waves done reading lA/lB before reuse
    float* epi = (float*)smem + wave * 1024;   // 16 rows x 64 cols fp32 (4 KB/wave)
    // C/D layout: col = lane&15, row = (lane>>4)*4 + reg  [m89-verified]
    const int cr = (lane >> 4) << 2;
    const int cc = lane & 15;
    const long hh_base = (col0 + nBase) >> 2;  // global h index base (16 h per wave)

    #pragma unroll
    for (int mi = 0; mi < 4; mi++) {
        // scatter this wave's 16x64 fp32 chunk to LDS (row-major, no pad)
        #pragma unroll
        for (int ni = 0; ni < 4; ni++)
            #pragma unroll
            for (int r = 0; r < 4; r++)
                epi[(cr + r) * 64 + cc + 16 * ni] = acc[mi][ni][r];
        // gather (row, h)-major: 4 gates contiguous; wave-local so no barrier needed
        #pragma unroll
        for (int it = 0; it < 4; it++) {
            int idx = it * 64 + lane;
            int rl = idx >> 4;        // 0..15 local batch row
            int hl = idx & 15;        // 0..15 local h
            float4 g4 = *(const float4*)&epi[rl * 64 + hl * 4];  // (i,f,o,c)
            long rg = row0 + mBase + mi * 16 + rl;
            long hg = hh_base + hl;
            float pcv = pc[rg * HID + hg];
            float vi = sigf(g4.x);
            float vf = sigf(g4.y);
            float vo = sigf(g4.z);
            float ct = tanhfast(g4.w);
            float ncf = vf * pcv + vi * ct;
            float nhf = vo * tanhfast(ncf);
            out[rg * HID + hg] = nhf;                              // next_h
            out[(size_t)BATCH * HID + rg * HID + hg] = ncf;        // next_c
        }
    }
}

extern "C" void kernel_launch(void* const* d_in, const int* in_sizes, int n_in,
                              void* d_out, int out_size, void* d_ws, size_t ws_size,
                              hipStream_t stream) {
    const float* x   = (const float*)d_in[0];
    const float* ph  = (const float*)d_in[1];
    const float* pc  = (const float*)d_in[2];
    const float* Wi  = (const float*)d_in[3];
    const float* Wf  = (const float*)d_in[4];
    const float* Wo  = (const float*)d_in[5];
    const float* Wc  = (const float*)d_in[6];

    // workspace (bf16): hx [4096,3072] | Wb [8192,3072] interleaved  (~75 MB)
    unsigned short* hx = (unsigned short*)d_ws;
    unsigned short* Wb = hx + (size_t)BATCH * GK;
    float* out = (float*)d_out;

    // one pack kernel: 9,437,184 float4 groups / 256 = 36864 blocks
    pack_all<<<36864, 256, 0, stream>>>((const float4*)ph, (const float4*)x,
                                        (const float4*)Wi, (const float4*)Wf,
                                        (const float4*)Wo, (const float4*)Wc,
                                        hx, Wb);

    // fused GEMM + LSTM -> fp32 next_h/next_c
    gemm_lstm<<<dim3(BATCH / 128, GN / 128), 256, 0, stream>>>(hx, Wb, pc, out);
}

// Round 4
// 456.770 us; speedup vs baseline: 1.1047x; 1.1047x over previous
//
#include <hip/hip_runtime.h>
#include <hip/hip_bf16.h>

// LSTM cell: B=4096, IN=1024, H=2048.
// gates = [prev_h | x] @ [W_i;W_f;W_o;W_c]^T  -> [4096, 8192]
// R4: single pack kernel (fp32->bf16), R2's known-good gemm_bt (68 VGPR, 264us),
// separate fp32-out lstm_ep. 3 launches total.

#define BATCH 4096
#define INW   1024
#define HID   2048
#define GK    3072   // HID + INW
#define GN    8192   // 4*HID

typedef __attribute__((ext_vector_type(8))) short short8;
typedef __attribute__((ext_vector_type(4))) float floatx4;

__device__ __forceinline__ unsigned short f2bf(float f) {
    union { float f; unsigned u; } v; v.f = f;
    unsigned r = v.u + 0x7FFFu + ((v.u >> 16) & 1u);
    return (unsigned short)(r >> 16);
}
__device__ __forceinline__ float bf2f(unsigned short u) {
    union { unsigned u; float f; } v; v.u = ((unsigned)u) << 16;
    return v.f;
}
__device__ __forceinline__ float sigf(float x) {
    return 1.0f / (1.0f + __expf(-x));
}
__device__ __forceinline__ float tanhfast(float x) {
    float t = __expf(fminf(fmaxf(2.0f * x, -30.0f), 30.0f));
    return (t - 1.0f) / (t + 1.0f);
}

// ---- single pack kernel: each thread converts 8 fp32 -> 8 bf16 (two float4 loads, one 16B store)
// float8-group counts: ph 4096*256=1048576 | x 4096*128=524288 | each W 2048*384=786432 (x4).
// All segment boundaries are multiples of 256 -> block-uniform branches.
__global__ __launch_bounds__(256) void pack_all(const float4* __restrict__ ph,
                                                const float4* __restrict__ x,
                                                const float4* __restrict__ Wi,
                                                const float4* __restrict__ Wf,
                                                const float4* __restrict__ Wo,
                                                const float4* __restrict__ Wc,
                                                unsigned short* __restrict__ hx,
                                                unsigned short* __restrict__ Wb) {
    long i = (long)blockIdx.x * 256 + threadIdx.x;
    const float4* src;
    unsigned short* dst;
    if (i < 1048576L) {            // prev_h [4096,2048] -> hx[:, 0:2048] (row restride)
        int r  = (int)(i >> 8);    // 256 groups per row
        int c8 = (int)(i & 255);
        src = ph + 2 * i;
        dst = hx + (size_t)r * GK + (size_t)c8 * 8;
    } else if (i < 1572864L) {     // x [4096,1024] -> hx[:, 2048:3072]
        long j = i - 1048576L;
        int r  = (int)(j >> 7);    // 128 groups per row
        int c8 = (int)(j & 127);
        src = x + 2 * j;
        dst = hx + (size_t)r * GK + HID + (size_t)c8 * 8;
    } else {                        // W_g [2048,3072] -> Wb + g*HID*GK (flat contiguous copy)
        long j = i - 1572864L;
        const float4* Wg;
        int g;
        if (j < 786432L)            { Wg = Wi; g = 0; }
        else if (j < 1572864L)      { Wg = Wf; g = 1; j -= 786432L; }
        else if (j < 2359296L)      { Wg = Wo; g = 2; j -= 1572864L; }
        else                        { Wg = Wc; g = 3; j -= 2359296L; }
        src = Wg + 2 * j;
        dst = Wb + (size_t)g * HID * GK + (size_t)j * 8;
    }
    float4 v0 = src[0];
    float4 v1 = src[1];
    unsigned short o[8];
    o[0] = f2bf(v0.x); o[1] = f2bf(v0.y); o[2] = f2bf(v0.z); o[3] = f2bf(v0.w);
    o[4] = f2bf(v1.x); o[5] = f2bf(v1.y); o[6] = f2bf(v1.z); o[7] = f2bf(v1.w);
    *(short8*)dst = *(const short8*)o;   // 16B store
}

__device__ __forceinline__ void gld16(const unsigned short* g, unsigned short* l) {
    __builtin_amdgcn_global_load_lds((const __attribute__((address_space(1))) unsigned int*)g,
                                     (__attribute__((address_space(3))) unsigned int*)l,
                                     16, 0, 0);
}

// ---- C[M,N] = A[M,K] * Bt[N,K]^T  (bf16 in, bf16 out, fp32 accumulate) — R2 known-good ----
__global__ __launch_bounds__(256) void gemm_bt(const unsigned short* __restrict__ A,
                                               const unsigned short* __restrict__ Bt,
                                               unsigned short* __restrict__ C) {
    __shared__ unsigned short lA[128 * 32];  // 8 KB
    __shared__ unsigned short lB[128 * 32];  // 8 KB
    const int tid  = threadIdx.x;
    const int wave = tid >> 6;
    const int lane = tid & 63;
    const long row0 = (long)blockIdx.x * 128;   // M tile
    const long col0 = (long)blockIdx.y * 128;   // N tile

    const int sr = tid >> 2;
    const int sk = (tid & 3) << 3;
    const unsigned short* gA0 = A  + (row0 + sr)      * GK + sk;
    const unsigned short* gA1 = A  + (row0 + 64 + sr) * GK + sk;
    const unsigned short* gB0 = Bt + (col0 + sr)      * GK + sk;
    const unsigned short* gB1 = Bt + (col0 + 64 + sr) * GK + sk;
    unsigned short* lA0 = &lA[wave * 512];
    unsigned short* lA1 = &lA[2048 + wave * 512];
    unsigned short* lB0 = &lB[wave * 512];
    unsigned short* lB1 = &lB[2048 + wave * 512];

    floatx4 acc[4][4];
    #pragma unroll
    for (int mi = 0; mi < 4; mi++)
        #pragma unroll
        for (int ni = 0; ni < 4; ni++)
            acc[mi][ni] = (floatx4)(0.0f);

    const int mBase = (wave >> 1) << 6;
    const int nBase = (wave & 1) << 6;
    const int fr = lane & 15;
    const int kq = (lane >> 4) << 3;

    for (int k0 = 0; k0 < GK; k0 += 32) {
        __syncthreads();
        gld16(gA0 + k0, lA0);
        gld16(gA1 + k0, lA1);
        gld16(gB0 + k0, lB0);
        gld16(gB1 + k0, lB1);
        __syncthreads();

        short8 af[4], bfv[4];
        #pragma unroll
        for (int mi = 0; mi < 4; mi++)
            af[mi] = *(const short8*)&lA[(mBase + mi * 16 + fr) * 32 + kq];
        #pragma unroll
        for (int ni = 0; ni < 4; ni++)
            bfv[ni] = *(const short8*)&lB[(nBase + ni * 16 + fr) * 32 + kq];
        #pragma unroll
        for (int mi = 0; mi < 4; mi++)
            #pragma unroll
            for (int ni = 0; ni < 4; ni++)
                acc[mi][ni] = __builtin_amdgcn_mfma_f32_16x16x32_bf16(af[mi], bfv[ni], acc[mi][ni], 0, 0, 0);
    }

    // C/D layout: col = lane&15, row = (lane>>4)*4 + reg  [m89-verified]
    const int cr = (lane >> 4) << 2;
    const int cc = lane & 15;
    #pragma unroll
    for (int mi = 0; mi < 4; mi++) {
        #pragma unroll
        for (int ni = 0; ni < 4; ni++) {
            long base = (row0 + mBase + mi * 16 + cr) * (long)GN + col0 + nBase + ni * 16 + cc;
            #pragma unroll
            for (int r = 0; r < 4; r++)
                C[base + (long)r * GN] = f2bf(acc[mi][ni][r]);
        }
    }
}

// ---- LSTM elementwise epilogue: gates[B,4H] bf16 (i,f,o,c slabs) -> FP32 next_h, next_c ----
__global__ __launch_bounds__(256) void lstm_ep(const unsigned short* __restrict__ gates,
                                               const float* __restrict__ prev_c,
                                               float* __restrict__ out) {
    const int i = blockIdx.x * 256 + threadIdx.x;     // one per 4 elements of B*H
    const int b = i >> 9;                             // H/4 = 512 groups per row
    const int h = (i & 511) << 2;
    const size_t gb = (size_t)b * GN + h;
    ushort4 gi = *(const ushort4*)&gates[gb];
    ushort4 gf = *(const ushort4*)&gates[gb + HID];
    ushort4 go = *(const ushort4*)&gates[gb + 2 * HID];
    ushort4 gc = *(const ushort4*)&gates[gb + 3 * HID];
    const size_t ob = (size_t)b * HID + h;
    float4 c4 = *(const float4*)&prev_c[ob];

    unsigned short giv[4] = {gi.x, gi.y, gi.z, gi.w};
    unsigned short gfv[4] = {gf.x, gf.y, gf.z, gf.w};
    unsigned short gov[4] = {go.x, go.y, go.z, go.w};
    unsigned short gcv[4] = {gc.x, gc.y, gc.z, gc.w};
    float cv[4] = {c4.x, c4.y, c4.z, c4.w};
    float nh[4], nc[4];
    #pragma unroll
    for (int j = 0; j < 4; j++) {
        float vi = sigf(bf2f(giv[j]));
        float vf = sigf(bf2f(gfv[j]));
        float vo = sigf(bf2f(gov[j]));
        float vc = tanhfast(bf2f(gcv[j]));
        float ncf = vf * cv[j] + vi * vc;
        float nhf = vo * tanhfast(ncf);
        nc[j] = ncf;
        nh[j] = nhf;
    }
    float4 vh = {nh[0], nh[1], nh[2], nh[3]};
    float4 vc4 = {nc[0], nc[1], nc[2], nc[3]};
    *(float4*)&out[ob] = vh;                                 // next_h (fp32)
    *(float4*)&out[(size_t)BATCH * HID + ob] = vc4;          // next_c (fp32)
}

extern "C" void kernel_launch(void* const* d_in, const int* in_sizes, int n_in,
                              void* d_out, int out_size, void* d_ws, size_t ws_size,
                              hipStream_t stream) {
    const float* x   = (const float*)d_in[0];
    const float* ph  = (const float*)d_in[1];
    const float* pc  = (const float*)d_in[2];
    const float* Wi  = (const float*)d_in[3];
    const float* Wf  = (const float*)d_in[4];
    const float* Wo  = (const float*)d_in[5];
    const float* Wc  = (const float*)d_in[6];

    // workspace (bf16): hx [4096,3072] | Wb [8192,3072] | gates [4096,8192]  (~143 MB)
    unsigned short* hx    = (unsigned short*)d_ws;
    unsigned short* Wb    = hx + (size_t)BATCH * GK;
    unsigned short* gates = Wb + (size_t)GN * GK;
    float* out = (float*)d_out;

    // one pack kernel: 4,718,592 float8 groups / 256 = 18432 blocks
    pack_all<<<18432, 256, 0, stream>>>((const float4*)ph, (const float4*)x,
                                        (const float4*)Wi, (const float4*)Wf,
                                        (const float4*)Wo, (const float4*)Wc,
                                        hx, Wb);

    // gates = hx @ W^T   [4096, 8192]
    gemm_bt<<<dim3(BATCH / 128, GN / 128), 256, 0, stream>>>(hx, Wb, gates);

    // elementwise LSTM -> fp32 outputs
    lstm_ep<<<(BATCH * HID / 4) / 256, 256, 0, stream>>>(gates, pc, out);
}

// Round 5
// 418.936 us; speedup vs baseline: 1.2044x; 1.0903x over previous
//
#include <hip/hip_runtime.h>
#include <hip/hip_bf16.h>

// LSTM cell: B=4096, IN=1024, H=2048.
// gates = [prev_h | x] @ [W_i;W_f;W_o;W_c]^T  -> [4096, 8192]
// R5: BK=64 GEMM (32 MFMA per barrier, swizzled LDS chunks), single pack kernel,
// separate fp32-out lstm_ep.

#define BATCH 4096
#define INW   1024
#define HID   2048
#define GK    3072   // HID + INW
#define GN    8192   // 4*HID

typedef __attribute__((ext_vector_type(8))) short short8;
typedef __attribute__((ext_vector_type(4))) float floatx4;

__device__ __forceinline__ unsigned short f2bf(float f) {
    union { float f; unsigned u; } v; v.f = f;
    unsigned r = v.u + 0x7FFFu + ((v.u >> 16) & 1u);
    return (unsigned short)(r >> 16);
}
__device__ __forceinline__ float bf2f(unsigned short u) {
    union { unsigned u; float f; } v; v.u = ((unsigned)u) << 16;
    return v.f;
}
__device__ __forceinline__ float sigf(float x) {
    return 1.0f / (1.0f + __expf(-x));
}
__device__ __forceinline__ float tanhfast(float x) {
    float t = __expf(fminf(fmaxf(2.0f * x, -30.0f), 30.0f));
    return (t - 1.0f) / (t + 1.0f);
}

// ---- single pack kernel: each thread converts 8 fp32 -> 8 bf16 (two float4 loads, one 16B store)
__global__ __launch_bounds__(256) void pack_all(const float4* __restrict__ ph,
                                                const float4* __restrict__ x,
                                                const float4* __restrict__ Wi,
                                                const float4* __restrict__ Wf,
                                                const float4* __restrict__ Wo,
                                                const float4* __restrict__ Wc,
                                                unsigned short* __restrict__ hx,
                                                unsigned short* __restrict__ Wb) {
    long i = (long)blockIdx.x * 256 + threadIdx.x;
    const float4* src;
    unsigned short* dst;
    if (i < 1048576L) {            // prev_h [4096,2048] -> hx[:, 0:2048] (row restride)
        int r  = (int)(i >> 8);
        int c8 = (int)(i & 255);
        src = ph + 2 * i;
        dst = hx + (size_t)r * GK + (size_t)c8 * 8;
    } else if (i < 1572864L) {     // x [4096,1024] -> hx[:, 2048:3072]
        long j = i - 1048576L;
        int r  = (int)(j >> 7);
        int c8 = (int)(j & 127);
        src = x + 2 * j;
        dst = hx + (size_t)r * GK + HID + (size_t)c8 * 8;
    } else {                        // W_g [2048,3072] -> Wb + g*HID*GK (flat contiguous copy)
        long j = i - 1572864L;
        const float4* Wg;
        int g;
        if (j < 786432L)            { Wg = Wi; g = 0; }
        else if (j < 1572864L)      { Wg = Wf; g = 1; j -= 786432L; }
        else if (j < 2359296L)      { Wg = Wo; g = 2; j -= 1572864L; }
        else                        { Wg = Wc; g = 3; j -= 2359296L; }
        src = Wg + 2 * j;
        dst = Wb + (size_t)g * HID * GK + (size_t)j * 8;
    }
    float4 v0 = src[0];
    float4 v1 = src[1];
    unsigned short o[8];
    o[0] = f2bf(v0.x); o[1] = f2bf(v0.y); o[2] = f2bf(v0.z); o[3] = f2bf(v0.w);
    o[4] = f2bf(v1.x); o[5] = f2bf(v1.y); o[6] = f2bf(v1.z); o[7] = f2bf(v1.w);
    *(short8*)dst = *(const short8*)o;
}

__device__ __forceinline__ void gld16(const unsigned short* g, unsigned short* l) {
    __builtin_amdgcn_global_load_lds((const __attribute__((address_space(1))) unsigned int*)g,
                                     (__attribute__((address_space(3))) unsigned int*)l,
                                     16, 0, 0);
}

// ---- C[M,N] = A[M,K] * Bt[N,K]^T  (bf16 in, bf16 out, fp32 acc), BK=64 ----
// LDS layout: [row][chunk-slot], 8 chunk-slots of 8 bf16 per row (128 B/row).
// Chunk swizzle: slot s of row r holds global k-chunk c with s = (c + r) & 7.
// Staging thread t (round j): local row r = j*32 + (t>>3), slot = t&7,
// global chunk c0 = ((t&7) - (t>>3)) & 7  (round-invariant since 32 % 8 == 0).
__global__ __launch_bounds__(256) void gemm_bt(const unsigned short* __restrict__ A,
                                               const unsigned short* __restrict__ Bt,
                                               unsigned short* __restrict__ C) {
    __shared__ unsigned short lA[128 * 64];  // 16 KB
    __shared__ unsigned short lB[128 * 64];  // 16 KB
    const int tid  = threadIdx.x;
    const int wave = tid >> 6;
    const int lane = tid & 63;
    const long row0 = (long)blockIdx.x * 128;   // M tile
    const long col0 = (long)blockIdx.y * 128;   // N tile

    const int r_loc = tid >> 3;                 // 0..31
    const int c0    = ((tid & 7) - r_loc) & 7;  // swizzled global chunk for this thread

    const unsigned short* gA[4];
    const unsigned short* gB[4];
    #pragma unroll
    for (int j = 0; j < 4; j++) {
        gA[j] = A  + (row0 + j * 32 + r_loc) * GK + c0 * 8;
        gB[j] = Bt + (col0 + j * 32 + r_loc) * GK + c0 * 8;
    }
    unsigned short* lAs = &lA[tid * 8];
    unsigned short* lBs = &lB[tid * 8];

    floatx4 acc[4][4];
    #pragma unroll
    for (int mi = 0; mi < 4; mi++)
        #pragma unroll
        for (int ni = 0; ni < 4; ni++)
            acc[mi][ni] = (floatx4)(0.0f);

    const int mBase = (wave >> 1) << 6;
    const int nBase = (wave & 1) << 6;
    const int fr = lane & 15;
    const int cq = lane >> 4;    // k-quad 0..3

    for (int k0 = 0; k0 < GK; k0 += 64) {
        __syncthreads();
        #pragma unroll
        for (int j = 0; j < 4; j++) gld16(gA[j] + k0, lAs + j * 2048);
        #pragma unroll
        for (int j = 0; j < 4; j++) gld16(gB[j] + k0, lBs + j * 2048);
        __syncthreads();

        #pragma unroll
        for (int ks = 0; ks < 2; ks++) {
            const int ci = ks * 4 + cq;
            short8 af[4], bfv[4];
            #pragma unroll
            for (int mi = 0; mi < 4; mi++) {
                int R = mBase + mi * 16 + fr;
                af[mi] = *(const short8*)&lA[R * 64 + (((ci + R) & 7) << 3)];
            }
            #pragma unroll
            for (int ni = 0; ni < 4; ni++) {
                int R = nBase + ni * 16 + fr;
                bfv[ni] = *(const short8*)&lB[R * 64 + (((ci + R) & 7) << 3)];
            }
            #pragma unroll
            for (int mi = 0; mi < 4; mi++)
                #pragma unroll
                for (int ni = 0; ni < 4; ni++)
                    acc[mi][ni] = __builtin_amdgcn_mfma_f32_16x16x32_bf16(af[mi], bfv[ni], acc[mi][ni], 0, 0, 0);
        }
    }

    // C/D layout: col = lane&15, row = (lane>>4)*4 + reg  [m89-verified]
    const int cr = (lane >> 4) << 2;
    const int cc = lane & 15;
    #pragma unroll
    for (int mi = 0; mi < 4; mi++) {
        #pragma unroll
        for (int ni = 0; ni < 4; ni++) {
            long base = (row0 + mBase + mi * 16 + cr) * (long)GN + col0 + nBase + ni * 16 + cc;
            #pragma unroll
            for (int r = 0; r < 4; r++)
                C[base + (long)r * GN] = f2bf(acc[mi][ni][r]);
        }
    }
}

// ---- LSTM elementwise epilogue: gates[B,4H] bf16 (i,f,o,c slabs) -> FP32 next_h, next_c ----
__global__ __launch_bounds__(256) void lstm_ep(const unsigned short* __restrict__ gates,
                                               const float* __restrict__ prev_c,
                                               float* __restrict__ out) {
    const int i = blockIdx.x * 256 + threadIdx.x;
    const int b = i >> 9;
    const int h = (i & 511) << 2;
    const size_t gb = (size_t)b * GN + h;
    ushort4 gi = *(const ushort4*)&gates[gb];
    ushort4 gf = *(const ushort4*)&gates[gb + HID];
    ushort4 go = *(const ushort4*)&gates[gb + 2 * HID];
    ushort4 gc = *(const ushort4*)&gates[gb + 3 * HID];
    const size_t ob = (size_t)b * HID + h;
    float4 c4 = *(const float4*)&prev_c[ob];

    unsigned short giv[4] = {gi.x, gi.y, gi.z, gi.w};
    unsigned short gfv[4] = {gf.x, gf.y, gf.z, gf.w};
    unsigned short gov[4] = {go.x, go.y, go.z, go.w};
    unsigned short gcv[4] = {gc.x, gc.y, gc.z, gc.w};
    float cv[4] = {c4.x, c4.y, c4.z, c4.w};
    float nh[4], nc[4];
    #pragma unroll
    for (int j = 0; j < 4; j++) {
        float vi = sigf(bf2f(giv[j]));
        float vf = sigf(bf2f(gfv[j]));
        float vo = sigf(bf2f(gov[j]));
        float vc = tanhfast(bf2f(gcv[j]));
        float ncf = vf * cv[j] + vi * vc;
        float nhf = vo * tanhfast(ncf);
        nc[j] = ncf;
        nh[j] = nhf;
    }
    float4 vh = {nh[0], nh[1], nh[2], nh[3]};
    float4 vc4 = {nc[0], nc[1], nc[2], nc[3]};
    *(float4*)&out[ob] = vh;
    *(float4*)&out[(size_t)BATCH * HID + ob] = vc4;
}

extern "C" void kernel_launch(void* const* d_in, const int* in_sizes, int n_in,
                              void* d_out, int out_size, void* d_ws, size_t ws_size,
                              hipStream_t stream) {
    const float* x   = (const float*)d_in[0];
    const float* ph  = (const float*)d_in[1];
    const float* pc  = (const float*)d_in[2];
    const float* Wi  = (const float*)d_in[3];
    const float* Wf  = (const float*)d_in[4];
    const float* Wo  = (const float*)d_in[5];
    const float* Wc  = (const float*)d_in[6];

    // workspace (bf16): hx [4096,3072] | Wb [8192,3072] | gates [4096,8192]  (~143 MB)
    unsigned short* hx    = (unsigned short*)d_ws;
    unsigned short* Wb    = hx + (size_t)BATCH * GK;
    unsigned short* gates = Wb + (size_t)GN * GK;
    float* out = (float*)d_out;

    pack_all<<<18432, 256, 0, stream>>>((const float4*)ph, (const float4*)x,
                                        (const float4*)Wi, (const float4*)Wf,
                                        (const float4*)Wo, (const float4*)Wc,
                                        hx, Wb);

    gemm_bt<<<dim3(BATCH / 128, GN / 128), 256, 0, stream>>>(hx, Wb, gates);

    lstm_ep<<<(BATCH * HID / 4) / 256, 256, 0, stream>>>(gates, pc, out);
}